// Round 9
// baseline (674.076 us; speedup 1.0000x reference)
//
#include <hip/hip_runtime.h>
#include <hip/hip_bf16.h>

#define THREADS 256
#define NB 256        // row buckets for uu CSR build
#define CHUNK 2048    // edges per partition block
#define EPT 8         // CHUNK / THREADS

// ---------------------------------------------------------------------------
// uu-CSR build: bucket hist -> scan -> LDS-staged partition -> per-bucket
// fine sort. All writes coalesced or confined to L2-resident windows.
// ---------------------------------------------------------------------------

__global__ __launch_bounds__(THREADS) void bucket_hist(
    const int* __restrict__ rows, int nnz, int bshift, int* __restrict__ bcnt)
{
    __shared__ int h[NB];
    h[threadIdx.x] = 0;
    __syncthreads();
    long long stride = (long long)gridDim.x * THREADS;
    for (long long e = (long long)blockIdx.x * THREADS + threadIdx.x; e < nnz; e += stride)
        atomicAdd(&h[rows[e] >> bshift], 1);
    __syncthreads();
    int v = h[threadIdx.x];
    if (v) atomicAdd(&bcnt[threadIdx.x], v);
}

__global__ void scan_buckets(const int* __restrict__ bcnt, int* __restrict__ bbase,
                             int* __restrict__ gcur, int* __restrict__ rp, int U_, int E_)
{
    if (threadIdx.x == 0 && blockIdx.x == 0) {
        int run = 0;
        for (int i = 0; i < NB; i++) { bbase[i] = run; gcur[i] = run; run += bcnt[i]; }
        bbase[NB] = run;
        rp[U_] = E_;
    }
}

// mid payload: [63:32]=val bits, [28:20]=row&(RPB-1), [19:0]=col
__global__ __launch_bounds__(THREADS) void partition_uu(
    const int* __restrict__ rows, const int* __restrict__ cols,
    const float* __restrict__ vals, int nnz, int bshift,
    unsigned long long* __restrict__ mid, int* __restrict__ gcur)
{
    __shared__ int hist[NB], lbase[NB], lcur[NB], gbase[NB];
    __shared__ unsigned long long stage[CHUNK];
    __shared__ int dst[CHUNK];
    int t = threadIdx.x;
    long long cb = (long long)blockIdx.x * CHUNK;
    hist[t] = 0; lcur[t] = 0;
    __syncthreads();

    int rl[EPT], cl[EPT], vb[EPT];
    #pragma unroll
    for (int j = 0; j < EPT; j++) {
        long long e = cb + j * THREADS + t;
        if (e < nnz) {
            rl[j] = rows[e]; cl[j] = cols[e]; vb[j] = __float_as_int(vals[e]);
            atomicAdd(&hist[rl[j] >> bshift], 1);
        } else rl[j] = -1;
    }
    __syncthreads();

    int v = hist[t];
    lbase[t] = v;
    __syncthreads();
    for (int off = 1; off < NB; off <<= 1) {
        int add = (t >= off) ? lbase[t - off] : 0;
        __syncthreads();
        lbase[t] += add;
        __syncthreads();
    }
    int excl = lbase[t] - v;
    int gb = 0;
    if (v) gb = atomicAdd(&gcur[t], v);
    gbase[t] = gb;
    lbase[t] = excl;
    __syncthreads();

    #pragma unroll
    for (int j = 0; j < EPT; j++) {
        if (rl[j] >= 0) {
            int b = rl[j] >> bshift;
            int rank = atomicAdd(&lcur[b], 1);
            int pos = lbase[b] + rank;
            stage[pos] = ((unsigned long long)(unsigned)vb[j] << 32)
                       | ((unsigned)(rl[j] & ((1 << bshift) - 1)) << 20)
                       | (unsigned)cl[j];
            dst[pos] = gbase[b] + rank;
        }
    }
    __syncthreads();
    int total = lbase[NB - 1] + hist[NB - 1];
    for (int i = t; i < total; i += THREADS)
        mid[dst[i]] = stage[i];
}

__global__ __launch_bounds__(THREADS) void fine_uu(
    const unsigned long long* __restrict__ mid, const int* __restrict__ bbase,
    int2* __restrict__ se, int* __restrict__ rp, int bshift)
{
    __shared__ int rcnt[512];
    __shared__ int sc[THREADS];
    int b = blockIdx.x, t = threadIdx.x;
    int s = bbase[b], e = bbase[b + 1];
    int rmask = (1 << bshift) - 1;
    rcnt[t] = 0; rcnt[t + 256] = 0;
    __syncthreads();
    for (int i = s + t; i < e; i += THREADS)
        atomicAdd(&rcnt[(int)(mid[i] >> 20) & rmask], 1);
    __syncthreads();
    int a0 = rcnt[2 * t], a1 = rcnt[2 * t + 1];
    int psum = a0 + a1;
    sc[t] = psum;
    __syncthreads();
    for (int off = 1; off < THREADS; off <<= 1) {
        int add = (t >= off) ? sc[t - off] : 0;
        __syncthreads();
        sc[t] += add;
        __syncthreads();
    }
    int pexcl = sc[t] - psum;
    int rowg = (b << bshift) + 2 * t;
    rp[rowg]     = s + pexcl;
    rp[rowg + 1] = s + pexcl + a0;
    rcnt[2 * t] = pexcl;
    rcnt[2 * t + 1] = pexcl + a0;
    __syncthreads();
    for (int i = s + t; i < e; i += THREADS) {
        unsigned long long w = mid[i];
        int rloc = (int)(w >> 20) & rmask;
        int pos = s + atomicAdd(&rcnt[rloc], 1);
        se[pos] = make_int2((int)(w & 0xFFFFF), (int)(w >> 32));
    }
}

// ---------------------------------------------------------------------------
// g-graph build (filtered): hist -> scan -> scatter
// ---------------------------------------------------------------------------

__global__ __launch_bounds__(THREADS) void hist_g(
    const int* __restrict__ rows, const int* __restrict__ cols,
    int nnz, int* __restrict__ cnt, int nU)
{
    int stride = gridDim.x * THREADS;
    for (int e = blockIdx.x * THREADS + threadIdx.x; e < nnz; e += stride) {
        int r = rows[e];
        if (r >= nU && cols[e] < nU) atomicAdd(&cnt[r - nU], 1);
    }
}

__global__ __launch_bounds__(THREADS) void scan_block_sums(
    const int* __restrict__ cnt, int* __restrict__ partial)
{
    __shared__ int lds[THREADS];
    int i = blockIdx.x * 512 + threadIdx.x * 2;
    lds[threadIdx.x] = cnt[i] + cnt[i + 1];
    __syncthreads();
    for (int off = 128; off > 0; off >>= 1) {
        if (threadIdx.x < off) lds[threadIdx.x] += lds[threadIdx.x + off];
        __syncthreads();
    }
    if (threadIdx.x == 0) partial[blockIdx.x] = lds[0];
}

__global__ void scan_partials(int* partial, int nb, int* rp, int n)
{
    if (threadIdx.x == 0 && blockIdx.x == 0) {
        int run = 0;
        for (int i = 0; i < nb; i++) { int v = partial[i]; partial[i] = run; run += v; }
        rp[n] = run;
    }
}

__global__ __launch_bounds__(THREADS) void scan_write(
    const int* __restrict__ cnt, const int* __restrict__ partial, int* __restrict__ rp)
{
    __shared__ int lds[THREADS];
    int t = threadIdx.x;
    int i = blockIdx.x * 512 + t * 2;
    int a0 = cnt[i], a1 = cnt[i + 1];
    int s = a0 + a1;
    lds[t] = s;
    __syncthreads();
    for (int off = 1; off < THREADS; off <<= 1) {
        int v = (t >= off) ? lds[t - off] : 0;
        __syncthreads();
        lds[t] += v;
        __syncthreads();
    }
    int excl = lds[t] - s;
    int base = partial[blockIdx.x];
    rp[i] = base + excl;
    rp[i + 1] = base + excl + a0;
}

__global__ __launch_bounds__(THREADS) void scatter_g(
    const int* __restrict__ rows, const int* __restrict__ cols,
    const float* __restrict__ vals, int nnz, int* __restrict__ cur,
    int2* __restrict__ se, int nU)
{
    int stride = gridDim.x * THREADS;
    for (int e = blockIdx.x * THREADS + threadIdx.x; e < nnz; e += stride) {
        int r = rows[e];
        if (r >= nU) {
            int c = cols[e];
            if (c < nU) {
                int p = atomicAdd(&cur[r - nU], 1);
                se[p] = make_int2(c, __float_as_int(vals[e]));
            }
        }
    }
}

// ---------------------------------------------------------------------------
// Gather SpMM v3: wave per row; lane = (g=lane>>4 edge sub-slot, fl=lane&15
// feature quad). Per slot one 16-lane float4 gather covers a full x-row;
// cols/vals distributed by shfl; 8 independent float4 accumulators keep
// 128 B/lane in flight. Cross-group shfl_xor reduce; g==0 stores float4.
// mode: 0 = y only, 1 = acc store, 2 = acc add, 3 = acc = 0.25*(ue+acc+a)
// ---------------------------------------------------------------------------
__global__ __launch_bounds__(THREADS) void spmm_csr3(
    const int* __restrict__ rp, const long long* __restrict__ se,
    const float* __restrict__ x, float* __restrict__ y,
    float* __restrict__ acc, const float* __restrict__ ue,
    int mode, int nrows)
{
    int w = (blockIdx.x * THREADS + threadIdx.x) >> 6;
    int lane = threadIdx.x & 63;
    if (w >= nrows) return;
    int s = rp[w], e = rp[w + 1];
    int g  = lane >> 4;        // which edge within a 4-edge slot group
    int fl = lane & 15;        // feature quad index (features fl*4..fl*4+3)

    const float4* __restrict__ x4 = (const float4*)x;

    float4 A0 = {0,0,0,0}, A1 = {0,0,0,0}, A2 = {0,0,0,0}, A3 = {0,0,0,0};
    float4 A4 = {0,0,0,0}, A5 = {0,0,0,0}, A6 = {0,0,0,0}, A7 = {0,0,0,0};

    for (int base = s; base < e; base += 64) {
        int avail = e - base;
        long long packed = 0;
        if (lane < avail)
            packed = __builtin_nontemporal_load(se + base + lane);
        int evc = (int)(packed & 0xffffffffLL);
        int evv = (int)(packed >> 32);
        int n = avail < 64 ? avail : 64;
        int nSlot = (n + 3) >> 2;              // 4 edges per slot
        int nIter = (nSlot + 7) & ~7;          // pad slots read col0/val0 -> +0
        for (int j0 = 0; j0 < nIter; j0 += 8) {
            int idx0 = (j0 + 0) * 4 + g, idx1 = (j0 + 1) * 4 + g;
            int idx2 = (j0 + 2) * 4 + g, idx3 = (j0 + 3) * 4 + g;
            int idx4 = (j0 + 4) * 4 + g, idx5 = (j0 + 5) * 4 + g;
            int idx6 = (j0 + 6) * 4 + g, idx7 = (j0 + 7) * 4 + g;
            int   c0 = __shfl(evc, idx0); float v0 = __int_as_float(__shfl(evv, idx0));
            int   c1 = __shfl(evc, idx1); float v1 = __int_as_float(__shfl(evv, idx1));
            int   c2 = __shfl(evc, idx2); float v2 = __int_as_float(__shfl(evv, idx2));
            int   c3 = __shfl(evc, idx3); float v3 = __int_as_float(__shfl(evv, idx3));
            int   c4 = __shfl(evc, idx4); float v4 = __int_as_float(__shfl(evv, idx4));
            int   c5 = __shfl(evc, idx5); float v5 = __int_as_float(__shfl(evv, idx5));
            int   c6 = __shfl(evc, idx6); float v6 = __int_as_float(__shfl(evv, idx6));
            int   c7 = __shfl(evc, idx7); float v7 = __int_as_float(__shfl(evv, idx7));
            float4 g0 = x4[((long long)c0 << 4) + fl];
            float4 g1 = x4[((long long)c1 << 4) + fl];
            float4 g2 = x4[((long long)c2 << 4) + fl];
            float4 g3 = x4[((long long)c3 << 4) + fl];
            float4 g4 = x4[((long long)c4 << 4) + fl];
            float4 g5 = x4[((long long)c5 << 4) + fl];
            float4 g6 = x4[((long long)c6 << 4) + fl];
            float4 g7 = x4[((long long)c7 << 4) + fl];
            A0.x += v0 * g0.x; A0.y += v0 * g0.y; A0.z += v0 * g0.z; A0.w += v0 * g0.w;
            A1.x += v1 * g1.x; A1.y += v1 * g1.y; A1.z += v1 * g1.z; A1.w += v1 * g1.w;
            A2.x += v2 * g2.x; A2.y += v2 * g2.y; A2.z += v2 * g2.z; A2.w += v2 * g2.w;
            A3.x += v3 * g3.x; A3.y += v3 * g3.y; A3.z += v3 * g3.z; A3.w += v3 * g3.w;
            A4.x += v4 * g4.x; A4.y += v4 * g4.y; A4.z += v4 * g4.z; A4.w += v4 * g4.w;
            A5.x += v5 * g5.x; A5.y += v5 * g5.y; A5.z += v5 * g5.z; A5.w += v5 * g5.w;
            A6.x += v6 * g6.x; A6.y += v6 * g6.y; A6.z += v6 * g6.z; A6.w += v6 * g6.w;
            A7.x += v7 * g7.x; A7.y += v7 * g7.y; A7.z += v7 * g7.z; A7.w += v7 * g7.w;
        }
    }

    float4 r;
    r.x = ((A0.x + A1.x) + (A2.x + A3.x)) + ((A4.x + A5.x) + (A6.x + A7.x));
    r.y = ((A0.y + A1.y) + (A2.y + A3.y)) + ((A4.y + A5.y) + (A6.y + A7.y));
    r.z = ((A0.z + A1.z) + (A2.z + A3.z)) + ((A4.z + A5.z) + (A6.z + A7.z));
    r.w = ((A0.w + A1.w) + (A2.w + A3.w)) + ((A4.w + A5.w) + (A6.w + A7.w));
    // cross-group reduce (groups 0..3 hold partials of the same features)
    r.x += __shfl_xor(r.x, 16); r.x += __shfl_xor(r.x, 32);
    r.y += __shfl_xor(r.y, 16); r.y += __shfl_xor(r.y, 32);
    r.z += __shfl_xor(r.z, 16); r.z += __shfl_xor(r.z, 32);
    r.w += __shfl_xor(r.w, 16); r.w += __shfl_xor(r.w, 32);

    if (g == 0) {
        long long oi = ((long long)w << 4) + fl;   // float4 index
        if (y) ((float4*)y)[oi] = r;
        if (mode == 1) {
            ((float4*)acc)[oi] = r;
        } else if (mode == 2) {
            float4 t = ((float4*)acc)[oi];
            t.x += r.x; t.y += r.y; t.z += r.z; t.w += r.w;
            ((float4*)acc)[oi] = t;
        } else if (mode == 3) {
            float4 t = ((float4*)acc)[oi];
            float4 u = ((const float4*)ue)[oi];
            t.x = 0.25f * (u.x + t.x + r.x);
            t.y = 0.25f * (u.y + t.y + r.y);
            t.z = 0.25f * (u.z + t.z + r.z);
            t.w = 0.25f * (u.w + t.w + r.w);
            ((float4*)acc)[oi] = t;
        }
    }
}

__global__ __launch_bounds__(THREADS) void final_dot_kernel(
    const float* __restrict__ au, const float* __restrict__ it,
    const int* __restrict__ users, const int* __restrict__ items,
    float* __restrict__ out, int B)
{
    int gid = blockIdx.x * THREADS + threadIdx.x;
    int b = gid >> 4;
    if (b >= B) return;
    int part = gid & 15;
    float4 uv = reinterpret_cast<const float4*>(au)[(long long)users[b] * 16 + part];
    float4 iv = reinterpret_cast<const float4*>(it)[(long long)items[b] * 16 + part];
    float s = uv.x * iv.x + uv.y * iv.y + uv.z * iv.z + uv.w * iv.w;
    s += __shfl_xor(s, 1);
    s += __shfl_xor(s, 2);
    s += __shfl_xor(s, 4);
    s += __shfl_xor(s, 8);
    if (part == 0) out[b] = s;
}

// ---------------------------------------------------------------------------
// Fallback (atomic path) in case ws/shape assumptions fail
// ---------------------------------------------------------------------------
__global__ __launch_bounds__(THREADS) void spmm_atomic_kernel(
    const int* __restrict__ rows, const int* __restrict__ cols,
    const float* __restrict__ vals, const float* __restrict__ x,
    float* __restrict__ y, int nnz)
{
    long long gid = (long long)blockIdx.x * THREADS + threadIdx.x;
    int e = (int)(gid >> 4);
    if (e >= nnz) return;
    int part = (int)(gid & 15);
    int r = rows[e];
    int c = cols[e];
    float v = vals[e];
    float4 xv = reinterpret_cast<const float4*>(x)[(long long)c * 16 + part];
    float* yp = y + (long long)r * 64 + part * 4;
    atomicAdd(yp + 0, v * xv.x);
    atomicAdd(yp + 1, v * xv.y);
    atomicAdd(yp + 2, v * xv.z);
    atomicAdd(yp + 3, v * xv.w);
}

__global__ __launch_bounds__(THREADS) void spmm_g_items_kernel(
    const int* __restrict__ rows, const int* __restrict__ cols,
    const float* __restrict__ vals, const float* __restrict__ x,
    float* __restrict__ y_items, int nnz, int nU)
{
    long long gid = (long long)blockIdx.x * THREADS + threadIdx.x;
    int e = (int)(gid >> 4);
    if (e >= nnz) return;
    int r = rows[e];
    if (r < nU) return;
    int c = cols[e];
    if (c >= nU) return;
    int part = (int)(gid & 15);
    float v = vals[e];
    float4 xv = reinterpret_cast<const float4*>(x)[(long long)c * 16 + part];
    float* yp = y_items + (long long)(r - nU) * 64 + part * 4;
    atomicAdd(yp + 0, v * xv.x);
    atomicAdd(yp + 1, v * xv.y);
    atomicAdd(yp + 2, v * xv.z);
    atomicAdd(yp + 3, v * xv.w);
}

__global__ __launch_bounds__(THREADS) void combine_kernel(
    const float4* __restrict__ e0, float4* __restrict__ e1,
    const float4* __restrict__ e2, const float4* __restrict__ e3, int n4)
{
    int i = blockIdx.x * THREADS + threadIdx.x;
    if (i >= n4) return;
    float4 a = e0[i], b = e1[i], c = e2[i], d = e3[i];
    e1[i] = make_float4(0.25f * (a.x + b.x + c.x + d.x), 0.25f * (a.y + b.y + c.y + d.y),
                        0.25f * (a.z + b.z + c.z + d.z), 0.25f * (a.w + b.w + c.w + d.w));
}

// ---------------------------------------------------------------------------

extern "C" void kernel_launch(void* const* d_in, const int* in_sizes, int n_in,
                              void* d_out, int out_size, void* d_ws, size_t ws_size,
                              hipStream_t stream) {
    const float* user_emb = (const float*)d_in[0];
    const int*   uu_rows  = (const int*)d_in[1];
    const int*   uu_cols  = (const int*)d_in[2];
    const float* uu_vals  = (const float*)d_in[3];
    const int*   g_rows   = (const int*)d_in[4];
    const int*   g_cols   = (const int*)d_in[5];
    const float* g_vals   = (const float*)d_in[6];
    const int*   users    = (const int*)d_in[7];
    const int*   items    = (const int*)d_in[8];

    const int U    = in_sizes[0] / 64;     // 131072
    const int E_UU = in_sizes[1];          // 4000000
    const int E_G  = in_sizes[4];          // 4000000
    const int B    = in_sizes[7];          // 8192
    const int M    = 32768;                // num_items (fixed per reference)

    const size_t EMB = (size_t)U * 64 * sizeof(float);   // 32 MB
    const size_t MB  = 1024 * 1024;

    char* ws = (char*)d_ws;

    float* ACC = (float*)(ws);
    float* P0  = (float*)(ws + EMB);
    float* P1  = (float*)(ws + 2 * EMB);
    unsigned long long* mid = (unsigned long long*)(ws);   // aliases ACC during build
    int*  cnt_g = (int*)(ws + EMB);
    int*  rp_g  = (int*)(ws + EMB + 512 * 1024);
    int*  cur_g = (int*)(ws + EMB + 1 * MB);
    int2* se_g  = (int2*)(ws + EMB + MB + 512 * 1024);
    float* IT   = (float*)(ws + EMB + 34 * MB);
    char* base3 = ws + 3 * EMB;
    int*  bcnt    = (int*)(base3);
    int*  gcur    = (int*)(base3 + 4096);
    int*  bbase   = (int*)(base3 + 8192);
    int*  partial = (int*)(base3 + 1 * MB);
    int*  rp_u  = (int*)(base3 + 1 * MB + 16 * 1024);
    int2* se_u  = (int2*)(base3 + 2 * MB + 16 * 1024);
    const size_t needCSR = 3 * EMB + 2 * MB + 16 * 1024 + (size_t)E_UU * 8 + 1024;

    int n4 = U * 16;

    bool newPath = (ws_size >= needCSR) && (U == 131072) &&
                   ((size_t)E_UU * 8 <= EMB) && (E_UU > 0);

    if (newPath) {
        const int bshift = 9;
        // ---- build uu CSR (bucket sort) ----
        hipMemsetAsync(bcnt, 0, NB * 4, stream);
        bucket_hist<<<1024, THREADS, 0, stream>>>(uu_rows, E_UU, bshift, bcnt);
        scan_buckets<<<1, 64, 0, stream>>>(bcnt, bbase, gcur, rp_u, U, E_UU);
        int nChunks = (E_UU + CHUNK - 1) / CHUNK;
        partition_uu<<<nChunks, THREADS, 0, stream>>>(uu_rows, uu_cols, uu_vals,
                                                      E_UU, bshift, mid, gcur);
        fine_uu<<<NB, THREADS, 0, stream>>>(mid, bbase, se_u, rp_u, bshift);

        // ---- 3 layers; ACC store/add/finalize folded into spmm ----
        spmm_csr3<<<U / 4, THREADS, 0, stream>>>(rp_u, (const long long*)se_u,
            user_emb, P0, ACC, (const float*)nullptr, 1, U);
        spmm_csr3<<<U / 4, THREADS, 0, stream>>>(rp_u, (const long long*)se_u,
            P0, P1, ACC, (const float*)nullptr, 2, U);
        spmm_csr3<<<U / 4, THREADS, 0, stream>>>(rp_u, (const long long*)se_u,
            P1, (float*)nullptr, ACC, user_emb, 3, U);

        // ---- build g (item-row) CSR, filtered ----
        hipMemsetAsync(cnt_g, 0, (size_t)M * 4, stream);
        hist_g<<<4096, THREADS, 0, stream>>>(g_rows, g_cols, E_G, cnt_g, U);
        scan_block_sums<<<M / 512, THREADS, 0, stream>>>(cnt_g, partial);
        scan_partials<<<1, 64, 0, stream>>>(partial, M / 512, rp_g, M);
        scan_write<<<M / 512, THREADS, 0, stream>>>(cnt_g, partial, rp_g);
        hipMemcpyAsync(cur_g, rp_g, (size_t)M * 4, hipMemcpyDeviceToDevice, stream);
        scatter_g<<<4096, THREADS, 0, stream>>>(g_rows, g_cols, g_vals, E_G, cur_g, se_g, U);

        // ---- item propagation + gamma ----
        spmm_csr3<<<M / 4, THREADS, 0, stream>>>(rp_g, (const long long*)se_g,
            ACC, IT, (float*)nullptr, (const float*)nullptr, 0, M);
        final_dot_kernel<<<(B * 16 + THREADS - 1) / THREADS, THREADS, 0, stream>>>(
            ACC, IT, users, items, (float*)d_out, B);
    } else {
        // ---- fallback: atomic path ----
        float* E1 = (float*)ws;
        float* E2 = (float*)(ws + EMB);
        float* E3 = (float*)(ws + 2 * EMB);
        float* IT2 = (float*)(ws + 3 * EMB);
        const size_t itBytes = (size_t)M * 64 * sizeof(float);
        int spmmGrid = (int)(((long long)E_UU * 16 + THREADS - 1) / THREADS);
        int gGrid    = (int)(((long long)E_G * 16 + THREADS - 1) / THREADS);

        hipMemsetAsync(E1, 0, EMB, stream);
        spmm_atomic_kernel<<<spmmGrid, THREADS, 0, stream>>>(uu_rows, uu_cols, uu_vals, user_emb, E1, E_UU);
        hipMemsetAsync(E2, 0, EMB, stream);
        spmm_atomic_kernel<<<spmmGrid, THREADS, 0, stream>>>(uu_rows, uu_cols, uu_vals, E1, E2, E_UU);
        hipMemsetAsync(E3, 0, EMB, stream);
        spmm_atomic_kernel<<<spmmGrid, THREADS, 0, stream>>>(uu_rows, uu_cols, uu_vals, E2, E3, E_UU);
        combine_kernel<<<(n4 + THREADS - 1) / THREADS, THREADS, 0, stream>>>(
            (const float4*)user_emb, (float4*)E1, (const float4*)E2, (const float4*)E3, n4);
        hipMemsetAsync(IT2, 0, itBytes, stream);
        spmm_g_items_kernel<<<gGrid, THREADS, 0, stream>>>(g_rows, g_cols, g_vals, E1, IT2, E_G, U);
        final_dot_kernel<<<(B * 16 + THREADS - 1) / THREADS, THREADS, 0, stream>>>(
            E1, IT2, users, items, (float*)d_out, B);
    }
}